// Round 9
// baseline (200.297 us; speedup 1.0000x reference)
//
#include <hip/hip_runtime.h>

#define HID 64
#define POS_DIM 32
#define IN_DIM 128

using short8 = __attribute__((ext_vector_type(8))) short;
using f32x4  = __attribute__((ext_vector_type(4))) float;

__device__ __forceinline__ float fsig(float v) {
    return 1.0f / (1.0f + __expf(-v));
}

// round-to-nearest-even fp32 -> bf16 bits
__device__ __forceinline__ unsigned short f2bf(float f) {
    unsigned int u = __float_as_uint(f);
    u = u + 0x7FFFu + ((u >> 16) & 1u);
    return (unsigned short)(u >> 16);
}
__device__ __forceinline__ float bf2f(unsigned short s) {
    return __uint_as_float(((unsigned int)s) << 16);
}
__device__ __forceinline__ float2 bfpair(unsigned int u) {
    return make_float2(__uint_as_float(u << 16),
                       __uint_as_float(u & 0xFFFF0000u));
}
__device__ __forceinline__ unsigned int pack2bf(float a, float b) {
    return (unsigned int)f2bf(a) | ((unsigned int)f2bf(b) << 16);
}

// ---------------- in-degree histogram ----------------
__global__ __launch_bounds__(256) void k_hist(const int* __restrict__ tp,
                                              int* cnt, int E) {
    int i = blockIdx.x * blockDim.x + threadIdx.x;
    if (i < E) atomicAdd(&cnt[tp[E + i]], 1);   // col = tp[1][i]
}

// ---------------- scan phase 1 ----------------
__global__ __launch_bounds__(256) void k_bsum(const int* __restrict__ cnt,
                                              int* __restrict__ bsum, int n) {
    int i = blockIdx.x * 256 + threadIdx.x;
    int v = (i < n) ? cnt[i] : 0;
    #pragma unroll
    for (int o = 32; o; o >>= 1) v += __shfl_down(v, o);
    __shared__ int w[4];
    int lane = threadIdx.x & 63, wid = threadIdx.x >> 6;
    if (lane == 0) w[wid] = v;
    __syncthreads();
    if (threadIdx.x == 0) bsum[blockIdx.x] = w[0] + w[1] + w[2] + w[3];
}

// ---------------- scan phase 2: off, cursor copy, dinv ----------------
__global__ __launch_bounds__(256) void k_scan2(const int* __restrict__ cnt,
                                               const int* __restrict__ bsum,
                                               int* __restrict__ off,
                                               int* __restrict__ cur,
                                               float* __restrict__ dinv,
                                               int n, int Etot) {
    __shared__ int s[256];
    __shared__ int wsum[4];
    int tid = threadIdx.x, bid = blockIdx.x;
    int p = 0;
    for (int t = tid; t < bid; t += 256) p += bsum[t];
    #pragma unroll
    for (int o = 32; o; o >>= 1) p += __shfl_down(p, o);
    int lane = tid & 63, wid = tid >> 6;
    if (lane == 0) wsum[wid] = p;
    __syncthreads();
    int bpre = wsum[0] + wsum[1] + wsum[2] + wsum[3];
    int i = bid * 256 + tid;
    int v = (i < n) ? cnt[i] : 0;
    s[tid] = v;
    __syncthreads();
    #pragma unroll
    for (int d = 1; d < 256; d <<= 1) {
        int t_ = (tid >= d) ? s[tid - d] : 0;
        __syncthreads();
        s[tid] += t_;
        __syncthreads();
    }
    if (i < n) {
        int ov = bpre + s[tid] - v;
        off[i]  = ov;
        cur[i]  = ov;
        dinv[i] = rsqrtf((float)(v + 1));
    }
    if (i == 0) off[n] = Etot;
}

// ---------------- fused sqdist + coef + CSR scatter (8 lanes/edge) ----------------
__global__ __launch_bounds__(256) void k_fill2(const int* __restrict__ tp,
                                               const float* __restrict__ pos,
                                               const float* __restrict__ dinv,
                                               int* cur,
                                               const float* em1w, const float* em1b,
                                               const float* em2w, const float* em2b,
                                               int4* __restrict__ csr, int E) {
    int lane = threadIdx.x & 63;
    int wid  = threadIdx.x >> 6;
    int sub  = lane >> 3;
    int j    = lane & 7;
    int e = (blockIdx.x * 4 + wid) * 8 + sub;
    if (e >= E) return;
    int row = tp[e];
    int col = tp[E + e];
    float4 a = ((const float4*)(pos + (size_t)row * POS_DIM))[j];
    float4 b = ((const float4*)(pos + (size_t)col * POS_DIM))[j];
    float dx = a.x - b.x, dy = a.y - b.y, dz = a.z - b.z, dw = a.w - b.w;
    float s = 0.0f;
    s = fmaf(dx, dx, s); s = fmaf(dy, dy, s);
    s = fmaf(dz, dz, s); s = fmaf(dw, dw, s);
    s += __shfl_xor(s, 1);
    s += __shfl_xor(s, 2);
    s += __shfl_xor(s, 4);
    if (j == 0) {
        float nrm = dinv[row] * dinv[col];
        float c1 = fsig(s * em1w[0] + em1b[0]) * nrm;
        float c2 = fsig(s * em2w[0] + em2b[0]) * nrm;
        int slot = atomicAdd(&cur[col], 1);
        csr[slot] = make_int4(row, __float_as_int(c1), __float_as_int(c2), 0);
    }
}

// ---------------- MFMA GEMM: H[n,64] = X[n,K] @ W[K,64], bf16 out ----------------
template<int K, bool IN_BF16>
__global__ __launch_bounds__(256) void k_gemm_mfma(const void* __restrict__ Xv,
                                                   const float* __restrict__ W,
                                                   unsigned short* __restrict__ H,
                                                   int n) {
    constexpr int RB   = K * 2;        // row bytes
    constexpr int CPR  = K / 8;        // 16B chunks per row
    __shared__ unsigned char lds[64 * RB * 2];
    unsigned char* As = lds;
    unsigned char* Bt = lds + 64 * RB;

    int tid  = threadIdx.x;
    int row0 = blockIdx.x * 64;

    for (int i = tid; i < 64 * CPR; i += 256) {
        int r  = i / CPR;
        int kb = i % CPR;
        uint4 val;
        if (row0 + r < n) {
            if (IN_BF16) {
                val = *(const uint4*)((const unsigned short*)Xv + (size_t)(row0 + r) * K + kb * 8);
            } else {
                const float* src = (const float*)Xv + (size_t)(row0 + r) * K + kb * 8;
                float4 f0 = ((const float4*)src)[0];
                float4 f1 = ((const float4*)src)[1];
                val.x = pack2bf(f0.x, f0.y); val.y = pack2bf(f0.z, f0.w);
                val.z = pack2bf(f1.x, f1.y); val.w = pack2bf(f1.z, f1.w);
            }
        } else {
            val = make_uint4(0, 0, 0, 0);
        }
        *(uint4*)(As + r * RB + ((kb ^ (r & 7)) << 4)) = val;
    }
    for (int i = tid; i < K * 16; i += 256) {
        int k  = i / 16;
        int c0 = (i % 16) * 4;
        float4 w = ((const float4*)W)[i];
        #pragma unroll
        for (int u = 0; u < 4; ++u) {
            int c = c0 + u;
            float vv = (u == 0) ? w.x : (u == 1) ? w.y : (u == 2) ? w.z : w.w;
            int byte = c * RB + ((((k * 2) >> 4) ^ (c & 7)) << 4) + ((k & 7) * 2);
            *(unsigned short*)(Bt + byte) = f2bf(vv);
        }
    }
    __syncthreads();

    int wv   = tid >> 6;
    int lane = tid & 63;
    int l15  = lane & 15;
    int g    = lane >> 4;

    f32x4 acc[4] = {{0,0,0,0},{0,0,0,0},{0,0,0,0},{0,0,0,0}};
    #pragma unroll
    for (int kk = 0; kk < K / 32; ++kk) {
        int kc = kk * 4 + g;
        int arow = wv * 16 + l15;
        short8 a = *(const short8*)(As + arow * RB + ((kc ^ (arow & 7)) << 4));
        #pragma unroll
        for (int cb = 0; cb < 4; ++cb) {
            int c = cb * 16 + l15;
            short8 b = *(const short8*)(Bt + c * RB + ((kc ^ (c & 7)) << 4));
            acc[cb] = __builtin_amdgcn_mfma_f32_16x16x32_bf16(a, b, acc[cb], 0, 0, 0);
        }
    }

    #pragma unroll
    for (int cb = 0; cb < 4; ++cb) {
        #pragma unroll
        for (int r = 0; r < 4; ++r) {
            int row = row0 + wv * 16 + g * 4 + r;
            if (row < n) H[(size_t)row * HID + cb * 16 + l15] = f2bf(acc[cb][r]);
        }
    }
}

// ---------------- gather-aggregate: 2 edges per wave-instruction ----------------
// lanes 0-31 handle even-slot edges, 32-63 odd-slot; lane q covers cols {2q,2q+1}.
__global__ __launch_bounds__(256) void k_agg(const int* __restrict__ off,
                                             const int4* __restrict__ csr,
                                             const unsigned short* __restrict__ h,
                                             const float* __restrict__ dinv,
                                             const float* __restrict__ bias,
                                             const float* emb,
                                             unsigned short* __restrict__ out,
                                             int n, int layer) {
    int wid  = threadIdx.x >> 6;
    int lane = threadIdx.x & 63;
    int half = lane >> 5;
    int q    = lane & 31;
    int i = blockIdx.x * 4 + wid;
    if (i >= n) return;
    float accx = 0.0f, accy = 0.0f;
    if (half == 0) {
        float di = dinv[i];
        float sc = fsig(emb[0]) * di * di;
        float2 bv = ((const float2*)bias)[q];
        float2 hv = bfpair(((const unsigned int*)(h + (size_t)i * HID))[q]);
        accx = fmaf(sc, hv.x, bv.x);
        accy = fmaf(sc, hv.y, bv.y);
    }
    int s  = off[i] + half;
    int s1 = off[i + 1];
    for (; s + 2 < s1; s += 4) {
        int4 ea = csr[s];
        int4 eb = csr[s + 2];
        float ca = __int_as_float(layer ? ea.z : ea.y);
        float cb = __int_as_float(layer ? eb.z : eb.y);
        float2 va = bfpair(((const unsigned int*)(h + (size_t)ea.x * HID))[q]);
        float2 vb = bfpair(((const unsigned int*)(h + (size_t)eb.x * HID))[q]);
        accx = fmaf(ca, va.x, accx); accy = fmaf(ca, va.y, accy);
        accx = fmaf(cb, vb.x, accx); accy = fmaf(cb, vb.y, accy);
    }
    if (s < s1) {
        int4 ea = csr[s];
        float ca = __int_as_float(layer ? ea.z : ea.y);
        float2 va = bfpair(((const unsigned int*)(h + (size_t)ea.x * HID))[q]);
        accx = fmaf(ca, va.x, accx); accy = fmaf(ca, va.y, accy);
    }
    accx += __shfl_down(accx, 32);
    accy += __shfl_down(accy, 32);
    if (half == 0)
        ((unsigned int*)out)[(size_t)i * (HID / 2) + q] = pack2bf(accx, accy);
}

// ---------------- final link predictor: 8 lanes per edge, bf16 h ----------------
__global__ __launch_bounds__(256) void k_predict(const int* __restrict__ pei,
                                                 const int* __restrict__ nei,
                                                 const unsigned short* __restrict__ h,
                                                 const float* __restrict__ pos,
                                                 const float* fcw, const float* fcb,
                                                 float* __restrict__ out, int Elp) {
    int j = threadIdx.x & 7;
    int e = blockIdx.x * 32 + (threadIdx.x >> 3);
    if (e >= 2 * Elp) return;
    int src, dst;
    if (e < Elp) { src = pei[e];        dst = pei[Elp + e]; }
    else         { src = nei[e - Elp];  dst = nei[e];       }
    uint4 hs = ((const uint4*)(h + (size_t)src * HID))[j];
    uint4 hd = ((const uint4*)(h + (size_t)dst * HID))[j];
    float p = 0.0f;
    {
        float2 a, b;
        a = bfpair(hs.x); b = bfpair(hd.x);
        p = fmaf(a.x, b.x, p); p = fmaf(a.y, b.y, p);
        a = bfpair(hs.y); b = bfpair(hd.y);
        p = fmaf(a.x, b.x, p); p = fmaf(a.y, b.y, p);
        a = bfpair(hs.z); b = bfpair(hd.z);
        p = fmaf(a.x, b.x, p); p = fmaf(a.y, b.y, p);
        a = bfpair(hs.w); b = bfpair(hd.w);
        p = fmaf(a.x, b.x, p); p = fmaf(a.y, b.y, p);
    }
    float4 pa = ((const float4*)(pos + (size_t)src * POS_DIM))[j];
    float4 pb = ((const float4*)(pos + (size_t)dst * POS_DIM))[j];
    float dx = pa.x - pb.x, dy = pa.y - pb.y, dz = pa.z - pb.z, dw = pa.w - pb.w;
    float pe = 0.0f;
    pe = fmaf(dx, dx, pe); pe = fmaf(dy, dy, pe);
    pe = fmaf(dz, dz, pe); pe = fmaf(dw, dw, pe);
    p  += __shfl_xor(p, 1);  pe += __shfl_xor(pe, 1);
    p  += __shfl_xor(p, 2);  pe += __shfl_xor(pe, 2);
    p  += __shfl_xor(p, 4);  pe += __shfl_xor(pe, 4);
    if (j == 0) out[e] = fcw[0] * p + fcw[1] * pe + fcb[0];
}

static inline size_t align16(size_t v) { return (v + 15) & ~(size_t)15; }

extern "C" void kernel_launch(void* const* d_in, const int* in_sizes, int n_in,
                              void* d_out, int out_size, void* d_ws, size_t ws_size,
                              hipStream_t stream) {
    const float* x    = (const float*)d_in[0];
    const float* pos  = (const float*)d_in[1];
    const int*   pei  = (const int*)d_in[2];
    const int*   nei  = (const int*)d_in[3];
    const int*   tp   = (const int*)d_in[4];
    const float* W1   = (const float*)d_in[5];
    const float* b1   = (const float*)d_in[6];
    const float* em1w = (const float*)d_in[7];
    const float* em1b = (const float*)d_in[8];
    const float* W2   = (const float*)d_in[9];
    const float* b2   = (const float*)d_in[10];
    const float* em2w = (const float*)d_in[11];
    const float* em2b = (const float*)d_in[12];
    const float* fcw  = (const float*)d_in[13];
    const float* fcb  = (const float*)d_in[14];
    float* outp = (float*)d_out;

    const int N   = in_sizes[0] / IN_DIM;   // 50000
    const int E   = in_sizes[4] / 2;        // 800000
    const int Elp = in_sizes[2] / 2;        // 100000
    const int NB  = (N + 255) / 256;

    char* base = (char*)d_ws;
    size_t o = 0;
    int4* csr = (int4*)(base + o);                        o += align16((size_t)E * 16);
    int*   cnt  = (int*)(base + o);                       o += align16((size_t)N * 4);
    int*   off  = (int*)(base + o);                       o += align16((size_t)(N + 1) * 4);
    int*   cur  = (int*)(base + o);                       o += align16((size_t)N * 4);
    int*   bsum = (int*)(base + o);                       o += align16((size_t)NB * 4);
    float* dinv = (float*)(base + o);                     o += align16((size_t)N * 4);
    unsigned short* hbuf = (unsigned short*)(base + o);   o += align16((size_t)N * HID * 2);
    unsigned short* obuf = (unsigned short*)(base + o);   o += align16((size_t)N * HID * 2);

    // ---- CSR build ----
    hipMemsetAsync(cnt, 0, (size_t)N * 4, stream);
    k_hist<<<(E + 255) / 256, 256, 0, stream>>>(tp, cnt, E);
    k_bsum<<<NB, 256, 0, stream>>>(cnt, bsum, N);
    k_scan2<<<NB, 256, 0, stream>>>(cnt, bsum, off, cur, dinv, N, E);
    k_fill2<<<(E + 31) / 32, 256, 0, stream>>>(tp, pos, dinv, cur,
                                               em1w, em1b, em2w, em2b, csr, E);

    // ---- layer 1 ----
    k_gemm_mfma<IN_DIM, false><<<(N + 63) / 64, 256, 0, stream>>>(x, W1, hbuf, N);
    k_agg<<<(N + 3) / 4, 256, 0, stream>>>(off, csr, hbuf, dinv, b1, em1b, obuf, N, 0);

    // ---- layer 2 ----
    k_gemm_mfma<HID, true><<<(N + 63) / 64, 256, 0, stream>>>(obuf, W2, hbuf, N);
    k_agg<<<(N + 3) / 4, 256, 0, stream>>>(off, csr, hbuf, dinv, b2, em2b, obuf, N, 1);

    // ---- predictor: layer-2 output is bf16 in obuf ----
    k_predict<<<(2 * Elp + 31) / 32, 256, 0, stream>>>(pei, nei, obuf,
                                                       pos, fcw, fcb, outp, Elp);
}

// Round 10
// 192.716 us; speedup vs baseline: 1.0393x; 1.0393x over previous
//
#include <hip/hip_runtime.h>
#include <hip/hip_fp16.h>

#define HID 64
#define POS_DIM 32
#define IN_DIM 128

using short8 = __attribute__((ext_vector_type(8))) short;
using f32x4  = __attribute__((ext_vector_type(4))) float;

__device__ __forceinline__ float fsig(float v) {
    return 1.0f / (1.0f + __expf(-v));
}

// round-to-nearest-even fp32 -> bf16 bits
__device__ __forceinline__ unsigned short f2bf(float f) {
    unsigned int u = __float_as_uint(f);
    u = u + 0x7FFFu + ((u >> 16) & 1u);
    return (unsigned short)(u >> 16);
}
__device__ __forceinline__ float bf2f(unsigned short s) {
    return __uint_as_float(((unsigned int)s) << 16);
}
__device__ __forceinline__ float2 bfpair(unsigned int u) {
    return make_float2(__uint_as_float(u << 16),
                       __uint_as_float(u & 0xFFFF0000u));
}
__device__ __forceinline__ unsigned int pack2bf(float a, float b) {
    return (unsigned int)f2bf(a) | ((unsigned int)f2bf(b) << 16);
}
// fp16 pair pack/unpack for CSR coefficients
__device__ __forceinline__ int pack2h(float a, float b) {
    __half2 h2 = __floats2half2_rn(a, b);
    return *reinterpret_cast<int*>(&h2);
}
__device__ __forceinline__ float cextract(int bits, int layer) {
    __half2 h2 = *reinterpret_cast<__half2*>(&bits);
    return layer ? __half2float(__high2half(h2)) : __half2float(__low2half(h2));
}

// ---------------- in-degree histogram ----------------
__global__ __launch_bounds__(256) void k_hist(const int* __restrict__ tp,
                                              int* cnt, int E) {
    int i = blockIdx.x * blockDim.x + threadIdx.x;
    if (i < E) atomicAdd(&cnt[tp[E + i]], 1);   // col = tp[1][i]
}

// ---------------- scan phase 1 ----------------
__global__ __launch_bounds__(256) void k_bsum(const int* __restrict__ cnt,
                                              int* __restrict__ bsum, int n) {
    int i = blockIdx.x * 256 + threadIdx.x;
    int v = (i < n) ? cnt[i] : 0;
    #pragma unroll
    for (int o = 32; o; o >>= 1) v += __shfl_down(v, o);
    __shared__ int w[4];
    int lane = threadIdx.x & 63, wid = threadIdx.x >> 6;
    if (lane == 0) w[wid] = v;
    __syncthreads();
    if (threadIdx.x == 0) bsum[blockIdx.x] = w[0] + w[1] + w[2] + w[3];
}

// ---------------- scan phase 2: off, cursor copy, dinv ----------------
__global__ __launch_bounds__(256) void k_scan2(const int* __restrict__ cnt,
                                               const int* __restrict__ bsum,
                                               int* __restrict__ off,
                                               int* __restrict__ cur,
                                               float* __restrict__ dinv,
                                               int n, int Etot) {
    __shared__ int s[256];
    __shared__ int wsum[4];
    int tid = threadIdx.x, bid = blockIdx.x;
    int p = 0;
    for (int t = tid; t < bid; t += 256) p += bsum[t];
    #pragma unroll
    for (int o = 32; o; o >>= 1) p += __shfl_down(p, o);
    int lane = tid & 63, wid = tid >> 6;
    if (lane == 0) wsum[wid] = p;
    __syncthreads();
    int bpre = wsum[0] + wsum[1] + wsum[2] + wsum[3];
    int i = bid * 256 + tid;
    int v = (i < n) ? cnt[i] : 0;
    s[tid] = v;
    __syncthreads();
    #pragma unroll
    for (int d = 1; d < 256; d <<= 1) {
        int t_ = (tid >= d) ? s[tid - d] : 0;
        __syncthreads();
        s[tid] += t_;
        __syncthreads();
    }
    if (i < n) {
        int ov = bpre + s[tid] - v;
        off[i]  = ov;
        cur[i]  = ov;
        dinv[i] = rsqrtf((float)(v + 1));
    }
    if (i == 0) off[n] = Etot;
}

// ---------------- fused sqdist + coef + CSR scatter (8 lanes/edge) ----------------
__global__ __launch_bounds__(256) void k_fill2(const int* __restrict__ tp,
                                               const float* __restrict__ pos,
                                               const float* __restrict__ dinv,
                                               int* cur,
                                               const float* em1w, const float* em1b,
                                               const float* em2w, const float* em2b,
                                               int2* __restrict__ csr, int E) {
    int lane = threadIdx.x & 63;
    int wid  = threadIdx.x >> 6;
    int sub  = lane >> 3;
    int j    = lane & 7;
    int e = (blockIdx.x * 4 + wid) * 8 + sub;
    if (e >= E) return;
    int row = tp[e];
    int col = tp[E + e];
    float4 a = ((const float4*)(pos + (size_t)row * POS_DIM))[j];
    float4 b = ((const float4*)(pos + (size_t)col * POS_DIM))[j];
    float dx = a.x - b.x, dy = a.y - b.y, dz = a.z - b.z, dw = a.w - b.w;
    float s = 0.0f;
    s = fmaf(dx, dx, s); s = fmaf(dy, dy, s);
    s = fmaf(dz, dz, s); s = fmaf(dw, dw, s);
    s += __shfl_xor(s, 1);
    s += __shfl_xor(s, 2);
    s += __shfl_xor(s, 4);
    if (j == 0) {
        float nrm = dinv[row] * dinv[col];
        float c1 = fsig(s * em1w[0] + em1b[0]) * nrm;
        float c2 = fsig(s * em2w[0] + em2b[0]) * nrm;
        int slot = atomicAdd(&cur[col], 1);
        csr[slot] = make_int2(row, pack2h(c1, c2));
    }
}

// ---------------- MFMA GEMM: H[n,64] = X[n,K] @ W[K,64], bf16 out ----------------
template<int K, bool IN_BF16>
__global__ __launch_bounds__(256) void k_gemm_mfma(const void* __restrict__ Xv,
                                                   const float* __restrict__ W,
                                                   unsigned short* __restrict__ H,
                                                   int n) {
    constexpr int RB   = K * 2;        // row bytes
    constexpr int CPR  = K / 8;        // 16B chunks per row
    __shared__ unsigned char lds[64 * RB * 2];
    unsigned char* As = lds;
    unsigned char* Bt = lds + 64 * RB;

    int tid  = threadIdx.x;
    int row0 = blockIdx.x * 64;

    for (int i = tid; i < 64 * CPR; i += 256) {
        int r  = i / CPR;
        int kb = i % CPR;
        uint4 val;
        if (row0 + r < n) {
            if (IN_BF16) {
                val = *(const uint4*)((const unsigned short*)Xv + (size_t)(row0 + r) * K + kb * 8);
            } else {
                const float* src = (const float*)Xv + (size_t)(row0 + r) * K + kb * 8;
                float4 f0 = ((const float4*)src)[0];
                float4 f1 = ((const float4*)src)[1];
                val.x = pack2bf(f0.x, f0.y); val.y = pack2bf(f0.z, f0.w);
                val.z = pack2bf(f1.x, f1.y); val.w = pack2bf(f1.z, f1.w);
            }
        } else {
            val = make_uint4(0, 0, 0, 0);
        }
        *(uint4*)(As + r * RB + ((kb ^ (r & 7)) << 4)) = val;
    }
    for (int i = tid; i < K * 16; i += 256) {
        int k  = i / 16;
        int c0 = (i % 16) * 4;
        float4 w = ((const float4*)W)[i];
        #pragma unroll
        for (int u = 0; u < 4; ++u) {
            int c = c0 + u;
            float vv = (u == 0) ? w.x : (u == 1) ? w.y : (u == 2) ? w.z : w.w;
            int byte = c * RB + ((((k * 2) >> 4) ^ (c & 7)) << 4) + ((k & 7) * 2);
            *(unsigned short*)(Bt + byte) = f2bf(vv);
        }
    }
    __syncthreads();

    int wv   = tid >> 6;
    int lane = tid & 63;
    int l15  = lane & 15;
    int g    = lane >> 4;

    f32x4 acc[4] = {{0,0,0,0},{0,0,0,0},{0,0,0,0},{0,0,0,0}};
    #pragma unroll
    for (int kk = 0; kk < K / 32; ++kk) {
        int kc = kk * 4 + g;
        int arow = wv * 16 + l15;
        short8 a = *(const short8*)(As + arow * RB + ((kc ^ (arow & 7)) << 4));
        #pragma unroll
        for (int cb = 0; cb < 4; ++cb) {
            int c = cb * 16 + l15;
            short8 b = *(const short8*)(Bt + c * RB + ((kc ^ (c & 7)) << 4));
            acc[cb] = __builtin_amdgcn_mfma_f32_16x16x32_bf16(a, b, acc[cb], 0, 0, 0);
        }
    }

    #pragma unroll
    for (int cb = 0; cb < 4; ++cb) {
        #pragma unroll
        for (int r = 0; r < 4; ++r) {
            int row = row0 + wv * 16 + g * 4 + r;
            if (row < n) H[(size_t)row * HID + cb * 16 + l15] = f2bf(acc[cb][r]);
        }
    }
}

// ---------------- gather-aggregate: uint-per-lane, 8 edges in flight per wave ----
// halves of the wave take even/odd CSR slots; lane q covers cols {2q,2q+1}.
__global__ __launch_bounds__(256) void k_agg(const int* __restrict__ off,
                                             const int2* __restrict__ csr,
                                             const unsigned short* __restrict__ h,
                                             const float* __restrict__ dinv,
                                             const float* __restrict__ bias,
                                             const float* emb,
                                             unsigned short* __restrict__ out,
                                             int n, int layer) {
    int wid  = threadIdx.x >> 6;
    int lane = threadIdx.x & 63;
    int half = lane >> 5;
    int q    = lane & 31;
    int i = blockIdx.x * 4 + wid;
    if (i >= n) return;
    float accx = 0.0f, accy = 0.0f;
    if (half == 0) {
        float di = dinv[i];
        float sc = fsig(emb[0]) * di * di;
        float2 bv = ((const float2*)bias)[q];
        float2 hv = bfpair(((const unsigned int*)(h + (size_t)i * HID))[q]);
        accx = fmaf(sc, hv.x, bv.x);
        accy = fmaf(sc, hv.y, bv.y);
    }
    int s  = off[i] + half;
    int s1 = off[i + 1];
    // 4 independent edge-gathers in flight per half-wave
    for (; s + 6 < s1; s += 8) {
        int2 ea = csr[s],     eb = csr[s + 2];
        int2 ec = csr[s + 4], ed = csr[s + 6];
        float ca = cextract(ea.y, layer);
        float cb = cextract(eb.y, layer);
        float cc = cextract(ec.y, layer);
        float cd = cextract(ed.y, layer);
        float2 va = bfpair(((const unsigned int*)(h + (size_t)ea.x * HID))[q]);
        float2 vb = bfpair(((const unsigned int*)(h + (size_t)eb.x * HID))[q]);
        float2 vc = bfpair(((const unsigned int*)(h + (size_t)ec.x * HID))[q]);
        float2 vd = bfpair(((const unsigned int*)(h + (size_t)ed.x * HID))[q]);
        accx = fmaf(ca, va.x, accx); accy = fmaf(ca, va.y, accy);
        accx = fmaf(cb, vb.x, accx); accy = fmaf(cb, vb.y, accy);
        accx = fmaf(cc, vc.x, accx); accy = fmaf(cc, vc.y, accy);
        accx = fmaf(cd, vd.x, accx); accy = fmaf(cd, vd.y, accy);
    }
    for (; s < s1; s += 2) {
        int2 ea = csr[s];
        float ca = cextract(ea.y, layer);
        float2 va = bfpair(((const unsigned int*)(h + (size_t)ea.x * HID))[q]);
        accx = fmaf(ca, va.x, accx); accy = fmaf(ca, va.y, accy);
    }
    accx += __shfl_down(accx, 32);
    accy += __shfl_down(accy, 32);
    if (half == 0)
        ((unsigned int*)out)[(size_t)i * (HID / 2) + q] = pack2bf(accx, accy);
}

// ---------------- final link predictor: 8 lanes per edge, bf16 h ----------------
__global__ __launch_bounds__(256) void k_predict(const int* __restrict__ pei,
                                                 const int* __restrict__ nei,
                                                 const unsigned short* __restrict__ h,
                                                 const float* __restrict__ pos,
                                                 const float* fcw, const float* fcb,
                                                 float* __restrict__ out, int Elp) {
    int j = threadIdx.x & 7;
    int e = blockIdx.x * 32 + (threadIdx.x >> 3);
    if (e >= 2 * Elp) return;
    int src, dst;
    if (e < Elp) { src = pei[e];        dst = pei[Elp + e]; }
    else         { src = nei[e - Elp];  dst = nei[e];       }
    uint4 hs = ((const uint4*)(h + (size_t)src * HID))[j];
    uint4 hd = ((const uint4*)(h + (size_t)dst * HID))[j];
    float p = 0.0f;
    {
        float2 a, b;
        a = bfpair(hs.x); b = bfpair(hd.x);
        p = fmaf(a.x, b.x, p); p = fmaf(a.y, b.y, p);
        a = bfpair(hs.y); b = bfpair(hd.y);
        p = fmaf(a.x, b.x, p); p = fmaf(a.y, b.y, p);
        a = bfpair(hs.z); b = bfpair(hd.z);
        p = fmaf(a.x, b.x, p); p = fmaf(a.y, b.y, p);
        a = bfpair(hs.w); b = bfpair(hd.w);
        p = fmaf(a.x, b.x, p); p = fmaf(a.y, b.y, p);
    }
    float4 pa = ((const float4*)(pos + (size_t)src * POS_DIM))[j];
    float4 pb = ((const float4*)(pos + (size_t)dst * POS_DIM))[j];
    float dx = pa.x - pb.x, dy = pa.y - pb.y, dz = pa.z - pb.z, dw = pa.w - pb.w;
    float pe = 0.0f;
    pe = fmaf(dx, dx, pe); pe = fmaf(dy, dy, pe);
    pe = fmaf(dz, dz, pe); pe = fmaf(dw, dw, pe);
    p  += __shfl_xor(p, 1);  pe += __shfl_xor(pe, 1);
    p  += __shfl_xor(p, 2);  pe += __shfl_xor(pe, 2);
    p  += __shfl_xor(p, 4);  pe += __shfl_xor(pe, 4);
    if (j == 0) out[e] = fcw[0] * p + fcw[1] * pe + fcb[0];
}

static inline size_t align16(size_t v) { return (v + 15) & ~(size_t)15; }

extern "C" void kernel_launch(void* const* d_in, const int* in_sizes, int n_in,
                              void* d_out, int out_size, void* d_ws, size_t ws_size,
                              hipStream_t stream) {
    const float* x    = (const float*)d_in[0];
    const float* pos  = (const float*)d_in[1];
    const int*   pei  = (const int*)d_in[2];
    const int*   nei  = (const int*)d_in[3];
    const int*   tp   = (const int*)d_in[4];
    const float* W1   = (const float*)d_in[5];
    const float* b1   = (const float*)d_in[6];
    const float* em1w = (const float*)d_in[7];
    const float* em1b = (const float*)d_in[8];
    const float* W2   = (const float*)d_in[9];
    const float* b2   = (const float*)d_in[10];
    const float* em2w = (const float*)d_in[11];
    const float* em2b = (const float*)d_in[12];
    const float* fcw  = (const float*)d_in[13];
    const float* fcb  = (const float*)d_in[14];
    float* outp = (float*)d_out;

    const int N   = in_sizes[0] / IN_DIM;   // 50000
    const int E   = in_sizes[4] / 2;        // 800000
    const int Elp = in_sizes[2] / 2;        // 100000
    const int NB  = (N + 255) / 256;

    char* base = (char*)d_ws;
    size_t o = 0;
    int2* csr = (int2*)(base + o);                        o += align16((size_t)E * 8);
    int*   cnt  = (int*)(base + o);                       o += align16((size_t)N * 4);
    int*   off  = (int*)(base + o);                       o += align16((size_t)(N + 1) * 4);
    int*   cur  = (int*)(base + o);                       o += align16((size_t)N * 4);
    int*   bsum = (int*)(base + o);                       o += align16((size_t)NB * 4);
    float* dinv = (float*)(base + o);                     o += align16((size_t)N * 4);
    unsigned short* hbuf = (unsigned short*)(base + o);   o += align16((size_t)N * HID * 2);
    unsigned short* obuf = (unsigned short*)(base + o);   o += align16((size_t)N * HID * 2);

    // ---- CSR build ----
    hipMemsetAsync(cnt, 0, (size_t)N * 4, stream);
    k_hist<<<(E + 255) / 256, 256, 0, stream>>>(tp, cnt, E);
    k_bsum<<<NB, 256, 0, stream>>>(cnt, bsum, N);
    k_scan2<<<NB, 256, 0, stream>>>(cnt, bsum, off, cur, dinv, N, E);
    k_fill2<<<(E + 31) / 32, 256, 0, stream>>>(tp, pos, dinv, cur,
                                               em1w, em1b, em2w, em2b, csr, E);

    // ---- layer 1 ----
    k_gemm_mfma<IN_DIM, false><<<(N + 63) / 64, 256, 0, stream>>>(x, W1, hbuf, N);
    k_agg<<<(N + 3) / 4, 256, 0, stream>>>(off, csr, hbuf, dinv, b1, em1b, obuf, N, 0);

    // ---- layer 2 ----
    k_gemm_mfma<HID, true><<<(N + 63) / 64, 256, 0, stream>>>(obuf, W2, hbuf, N);
    k_agg<<<(N + 3) / 4, 256, 0, stream>>>(off, csr, hbuf, dinv, b2, em2b, obuf, N, 1);

    // ---- predictor: layer-2 output is bf16 in obuf ----
    k_predict<<<(2 * Elp + 31) / 32, 256, 0, stream>>>(pei, nei, obuf,
                                                       pos, fcw, fcb, outp, Elp);
}